// Round 10
// baseline (1308.808 us; speedup 1.0000x reference)
//
#include <hip/hip_runtime.h>

// SNN: T=200, B=256, IN=784, N=1024, OUT=10
// W_rec = -0.5*(ones - I) => prev@W_rec = -0.5*(S_b - prev[b,j])  (exact in
// fp32). net_in[t] = x_t @ W_in is time-independent => one fp32 GEMM up
// front into d_out's hidden_spikes region, then an in-place spike scan.
//
// NUMERICS CONTRACT: dynamics are knife-edge (absmax 512 of 611 = one
// marginal spike-step flip vs BLAS summation order). The GEMM keeps a single
// ascending-k fmaf chain per output element — bit-identical across rounds.
// No MFMA/bf16, no split-K, no reassociation, true division in the scan.
// Block-wide spike count S is a sum of integer-valued floats (<=1024):
// exact under ANY summation order -> reduction implementation is free.
//
// v10 state of knowledge (all counters-measured):
//  GEMM: v0 structure (80 VGPR, 8x8 micro, reg-prefetch, 2 syncthreads/tile,
//  m-fast grid) is the probed optimum: 908us, VALUBusy 77%. Every deviation
//  lost (dbuf v2/v3: spill; DMA v4/v6: VGPR cliff; 4x8 v5/v7: LDS wall).
//  SCAN: barrier-coupled multi-wave scans measure ~3300 cyc/step vs <600
//  modeled (v8: 16-wave 366us; v9: 8-wave+depth-4 prefetch 276us) — the
//  8-wave barrier structure itself is the cost. v10 removes the structure:
//  ONE wave per batch row, 16 neurons/thread, S via ballot+popcount on the
//  scalar pipe. No barrier, no LDS, no cross-wave dependency. Per-neuron
//  update chain verbatim -> bit-identical dynamics.

#define TT 200
#define BB 256
#define KK 784
#define NN 1024
#define OO 10

// ---------------- Phase 1: net = X(51200x784) @ W(784x1024), fp32 ----------
// v0 kernel verbatim; m-block on blockIdx.x (fast axis). Measured 908us.
__global__ __launch_bounds__(256)
void gemm_net(const float* __restrict__ X, const float* __restrict__ W,
              float* __restrict__ C) {
  __shared__ float As[16][128];   // [k][m] (A staged transposed)
  __shared__ float Bs[16][128];   // [k][n]
  float4 (*As4)[32] = (float4(*)[32])As;
  float4 (*Bs4)[32] = (float4(*)[32])Bs;

  const int tid = threadIdx.x;
  const int m0 = blockIdx.x * 128;     // 400 m-blocks (fast axis)
  const int n0 = blockIdx.y * 128;     // 8 n-blocks   (slow axis)
  const int tx = tid & 15;             // cols tx*4, 64+tx*4
  const int ty = tid >> 4;             // rows ty*4, 64+ty*4
  const int arow = tid >> 1;           // 0..127
  const int ak   = (tid & 1) * 8;      // 0 or 8
  const int brow = tid >> 5;           // 0..7 (and +8)
  const int bc   = (tid & 31) * 4;     // 0..124

  const float* ap = X + (size_t)(m0 + arow) * KK + ak;
  const float* bp = W + (size_t)brow * NN + n0 + bc;

  // preload tile 0 into registers (live across compute: 16 regs + 64 acc
  // = the measured 80-VGPR optimum)
  float4 a0 = *(const float4*)(ap);
  float4 a1 = *(const float4*)(ap + 4);
  float4 b0 = *(const float4*)(bp);
  float4 b1 = *(const float4*)(bp + 8 * NN);

  float acc[2][2][4][4] = {};

  for (int k0 = 0; k0 < KK; k0 += 16) {
    __syncthreads();                   // previous tile's LDS reads done
    As[ak + 0][arow] = a0.x;           // bank=arow%32, 2-way (free)
    As[ak + 1][arow] = a0.y;
    As[ak + 2][arow] = a0.z;
    As[ak + 3][arow] = a0.w;
    As[ak + 4][arow] = a1.x;
    As[ak + 5][arow] = a1.y;
    As[ak + 6][arow] = a1.z;
    As[ak + 7][arow] = a1.w;
    *(float4*)&Bs[brow][bc] = b0;      // lane-consecutive: conflict-free
    *(float4*)&Bs[brow + 8][bc] = b1;
    __syncthreads();

    // prefetch next tile (latency overlapped by the 1024 FMAs below)
    if (k0 + 16 < KK) {
      ap += 16;
      bp += 16 * NN;
      a0 = *(const float4*)(ap);
      a1 = *(const float4*)(ap + 4);
      b0 = *(const float4*)(bp);
      b1 = *(const float4*)(bp + 8 * NN);
    }

#pragma unroll
    for (int k = 0; k < 16; ++k) {
      float4 A0 = As4[k][ty];          // broadcast (free)
      float4 A1 = As4[k][16 + ty];
      float4 B0 = Bs4[k][tx];          // 2-way (free)
      float4 B1 = Bs4[k][16 + tx];
      float av[2][4] = {{A0.x, A0.y, A0.z, A0.w}, {A1.x, A1.y, A1.z, A1.w}};
      float bv[2][4] = {{B0.x, B0.y, B0.z, B0.w}, {B1.x, B1.y, B1.z, B1.w}};
#pragma unroll
      for (int qi = 0; qi < 2; ++qi)
#pragma unroll
        for (int qj = 0; qj < 2; ++qj)
#pragma unroll
          for (int i = 0; i < 4; ++i)
#pragma unroll
            for (int j = 0; j < 4; ++j)
              acc[qi][qj][i][j] =
                  fmaf(av[qi][i], bv[qj][j], acc[qi][qj][i][j]);
    }
  }
#pragma unroll
  for (int qi = 0; qi < 2; ++qi)
#pragma unroll
    for (int i = 0; i < 4; ++i) {
      const int r = m0 + qi * 64 + ty * 4 + i;
#pragma unroll
      for (int qj = 0; qj < 2; ++qj) {
        float4 v = {acc[qi][qj][i][0], acc[qi][qj][i][1],
                    acc[qi][qj][i][2], acc[qi][qj][i][3]};
        *(float4*)(C + (size_t)r * NN + n0 + qj * 64 + tx * 4) = v;
      }
    }
}

// set float4 component by compile-time index (valid assignment expression)
#define F4SET(v, e, val)                                                   \
  ((e) == 0 ? ((v).x = (val))                                              \
            : (e) == 1 ? ((v).y = (val))                                   \
                       : (e) == 2 ? ((v).z = (val)) : ((v).w = (val)))
#define F4GET(v, e) ((e) == 0 ? (v).x : (e) == 1 ? (v).y : (e) == 2 ? (v).z : (v).w)

// ---------------- Phase 2: sequential scan, ONE WAVE per batch row ---------
// 64 threads, 16 neurons/thread (j = c*256 + lane*4 + e, c=0..3, e=0..3).
// No barrier, no LDS: S = sum_u popcll(ballot(spike_u)) — 16 scalar-pipe
// popcounts, integer-exact, identical value to the old cross-wave reduce.
// Per-neuron update chain is verbatim from v9 -> bit-identical dynamics.
// Depth-2 float4 prefetch (named parity banks, compile-time indexed) gives
// ~2 step-times (~2000 cyc) of load-latency cover.
__global__ __launch_bounds__(64)
void snn_scan(float* __restrict__ hid, const float* __restrict__ Wout,
              float* __restrict__ logits) {
  constexpr float V_REST = -65.0f, THRESH0 = -50.0f, TAU_M = 20.0f,
                  TAU_TH = 100.0f, BETA = 5.0f, DT = 1.0f;
  const int b = blockIdx.x;
  const int lane = threadIdx.x;              // 0..63
  const size_t rowbase = (size_t)b * NN + (size_t)lane * 4;
  const size_t STEP = (size_t)BB * NN;

  float mp[16], th[16], prev[16], cnt[16];
#pragma unroll
  for (int u = 0; u < 16; ++u) {
    mp[u] = V_REST; th[u] = THRESH0; prev[u] = 0.0f; cnt[u] = 0.0f;
  }
  float S = 0.0f;

  // depth-2 prefetch: parity banks p0 (even t), p1 (odd t)
  float4 p0[4], p1[4];
#pragma unroll
  for (int c = 0; c < 4; ++c) {
    p0[c] = *(const float4*)&hid[rowbase + c * 256];          // t = 0
    p1[c] = *(const float4*)&hid[STEP + rowbase + c * 256];   // t = 1
  }

  // One time-step: consumes net from P (loaded 2 steps earlier), updates 16
  // neurons (chain identical to v9), stores spikes, re-issues P <- t+2,
  // then S <- ballot/popcount sum (used by step t+1).
#define SCAN_STEP(t, P)                                                    \
  do {                                                                     \
    int Si = 0;                                                            \
    _Pragma("unroll") for (int c = 0; c < 4; ++c) {                        \
      float4 f4;                                                           \
      _Pragma("unroll") for (int e = 0; e < 4; ++e) {                      \
        const int u = c * 4 + e;                                           \
        float net = F4GET(P[c], e);                                        \
        float rec = -0.5f * (S - prev[u]);                                 \
        float nv = net + rec;                                              \
        float m = mp[u] + (V_REST - mp[u]) / TAU_M;                        \
        m = m + nv * DT;                                                   \
        bool sp = (m >= th[u]);                                            \
        float f = sp ? 1.0f : 0.0f;                                        \
        th[u] = (th[u] + BETA * f) - ((th[u] - THRESH0) / TAU_TH) * DT;    \
        mp[u] = sp ? V_REST : m;                                           \
        cnt[u] += f;                                                       \
        prev[u] = f;                                                       \
        Si += __popcll(__ballot(sp));                                      \
        F4SET(f4, e, f);                                                   \
      }                                                                    \
      *(float4*)&hid[(size_t)(t) * STEP + rowbase + c * 256] = f4;         \
    }                                                                      \
    if ((t) + 2 < TT) {                                                    \
      _Pragma("unroll") for (int c = 0; c < 4; ++c)                        \
        P[c] = *(const float4*)&hid[(size_t)((t) + 2) * STEP + rowbase +   \
                                    c * 256];                              \
    }                                                                      \
    S = (float)Si;                                                         \
  } while (0)

  for (int t = 0; t < TT; t += 2) {   // TT=200: 100 iterations, no tail
    SCAN_STEP(t + 0, p0);
    SCAN_STEP(t + 1, p1);
  }
#undef SCAN_STEP

  // logits[b,o] = sum_j cnt[b,j] * Wout[j,o]  (order change ~1e-3 on O(1e4)
  // logits; no feedback into dynamics). Wave-local shfl tree, lane0 stores.
  float lg[OO];
#pragma unroll
  for (int o = 0; o < OO; ++o) lg[o] = 0.0f;
#pragma unroll
  for (int c = 0; c < 4; ++c)
#pragma unroll
    for (int e = 0; e < 4; ++e) {
      const int u = c * 4 + e;
      const int j = c * 256 + lane * 4 + e;
#pragma unroll
      for (int o = 0; o < OO; ++o)
        lg[o] = fmaf(cnt[u], Wout[(size_t)j * OO + o], lg[o]);
    }
#pragma unroll
  for (int o = 0; o < OO; ++o) {
    float v = lg[o];
#pragma unroll
    for (int d = 32; d > 0; d >>= 1) v += __shfl_down(v, d, 64);
    if (lane == 0) logits[(size_t)b * OO + o] = v;
  }
}

extern "C" void kernel_launch(void* const* d_in, const int* in_sizes, int n_in,
                              void* d_out, int out_size, void* d_ws,
                              size_t ws_size, hipStream_t stream) {
  const float* X    = (const float*)d_in[0];  // input_spikes [200][256][784]
  const float* Win  = (const float*)d_in[1];  // [784][1024]
  // d_in[2] = W_rec — unused (exact closed form)
  const float* Wout = (const float*)d_in[3];  // [1024][10]

  float* logits = (float*)d_out;              // [256][10]
  float* hid    = (float*)d_out + BB * OO;    // [200][256][1024]

  dim3 g1(TT * BB / 128, NN / 128);           // 400 x 8 (m fast)
  gemm_net<<<g1, 256, 0, stream>>>(X, Win, hid);
  snn_scan<<<BB, 64, 0, stream>>>(hid, Wout, logits);
}